// Round 1
// baseline (1634.107 us; speedup 1.0000x reference)
//
#include <hip/hip_runtime.h>
#include <hip/hip_bf16.h>

// Problem constants (PolarNet): B=16, C=256, H=80, W=80, N=6400
constexpr int BATCH = 16;
constexpr int CH    = 256;
constexpr int HH    = 80;
constexpr int WW    = 80;
constexpr int NPIX  = HH * WW;          // 6400
constexpr int NTILE = 16;               // pixels per block in kernels C/E
constexpr int NT    = NPIX / NTILE;     // 400 tiles

// ---------------------------------------------------------------------------
// Kernel A: q/k/v projection, tiled fp32 GEMM.
// out[b][n][o] = sum_c W[o][c] * x[b][c][n] + bias[o]
// grid: (NPIX/64, CH/64, cnb*3)   block: 256
// ---------------------------------------------------------------------------
#define TN 64
#define TO 64
#define TK 32

__global__ __launch_bounds__(256) void qkv_gemm(
    const float* __restrict__ x,
    const float* __restrict__ Wq, const float* __restrict__ bq,
    const float* __restrict__ Wk, const float* __restrict__ bk,
    const float* __restrict__ Wv, const float* __restrict__ bv,
    float* __restrict__ qo, float* __restrict__ ko, float* __restrict__ vo,
    int b0)
{
    const int m  = blockIdx.z % 3;
    const int bl = blockIdx.z / 3;
    const int b  = b0 + bl;
    const float* Wm = (m == 0) ? Wq : (m == 1) ? Wk : Wv;
    const float* bm = (m == 0) ? bq : (m == 1) ? bk : bv;
    float* out = (m == 0) ? qo : (m == 1) ? ko : vo;
    out += (size_t)bl * NPIX * CH;
    const float* xb = x + (size_t)b * CH * NPIX;

    __shared__ float xs[TK][TN];        // [c][n]
    __shared__ float wsh[TK][TO + 1];   // [c][o], padded

    const int n0  = blockIdx.x * TN;
    const int o0  = blockIdx.y * TO;
    const int tid = threadIdx.x;
    const int tx  = tid % 16;   // o sub-block
    const int ty  = tid / 16;   // n sub-block

    float acc[4][4] = {};

    for (int ck = 0; ck < CH; ck += TK) {
        #pragma unroll
        for (int t = 0; t < (TK * TN) / 256; ++t) {
            int idx = tid + t * 256;
            int cc = idx / TN, nn = idx % TN;
            xs[cc][nn] = xb[(size_t)(ck + cc) * NPIX + n0 + nn];
        }
        #pragma unroll
        for (int t = 0; t < (TK * TO) / 256; ++t) {
            int idx = tid + t * 256;
            int oo = idx / TK, cc = idx % TK;
            wsh[cc][oo] = Wm[(size_t)(o0 + oo) * CH + ck + cc];
        }
        __syncthreads();
        #pragma unroll
        for (int kk = 0; kk < TK; ++kk) {
            float a[4], w[4];
            #pragma unroll
            for (int i = 0; i < 4; ++i) a[i] = xs[kk][ty * 4 + i];
            #pragma unroll
            for (int j = 0; j < 4; ++j) w[j] = wsh[kk][tx * 4 + j];
            #pragma unroll
            for (int i = 0; i < 4; ++i)
                #pragma unroll
                for (int j = 0; j < 4; ++j)
                    acc[i][j] += a[i] * w[j];
        }
        __syncthreads();
    }

    #pragma unroll
    for (int i = 0; i < 4; ++i) {
        int n = n0 + ty * 4 + i;
        #pragma unroll
        for (int j = 0; j < 4; ++j) {
            int o = o0 + tx * 4 + j;
            out[(size_t)n * CH + o] = acc[i][j] + bm[o];
        }
    }
}

// ---------------------------------------------------------------------------
// Kernel B: scores[b][n][j] = dot(q[b][n][:], k[b][nbr(n,j)][:]) over CH
// Also writes output0 (center, others_mean).
// grid: (NPIX/4, cnb)  block: 256 (4 waves, one pixel per wave)
// ---------------------------------------------------------------------------
__global__ __launch_bounds__(256) void scores_kernel(
    const float* __restrict__ q, const float* __restrict__ k,
    float* __restrict__ scores,   // [cnb][NPIX][9]
    float* __restrict__ out0,     // [BATCH][NPIX][2]
    int b0)
{
    const int wave = threadIdx.x / 64;
    const int lane = threadIdx.x % 64;
    const int n  = blockIdx.x * 4 + wave;
    const int bl = blockIdx.y;
    const int b  = b0 + bl;

    const float* qb = q + ((size_t)bl * NPIX + n) * CH;
    const float* kb = k + (size_t)bl * NPIX * CH;

    const float4 qv = *(const float4*)(qb + 4 * lane);
    const int r = n / WW, col = n % WW;

    float s[9];
    float ssum = 0.f;
    #pragma unroll
    for (int j = 0; j < 9; ++j) {
        int rr = min(max(r + j / 3 - 1, 0), HH - 1);
        int c2 = min(max(col + j % 3 - 1, 0), WW - 1);
        int nbr = rr * WW + c2;
        const float4 kv = *(const float4*)(kb + (size_t)nbr * CH + 4 * lane);
        float d = qv.x * kv.x + qv.y * kv.y + qv.z * kv.z + qv.w * kv.w;
        #pragma unroll
        for (int off = 32; off >= 1; off >>= 1) d += __shfl_xor(d, off, 64);
        s[j] = d;
        ssum += d;
    }
    if (lane == 0) {
        float* sp = scores + ((size_t)bl * NPIX + n) * 9;
        #pragma unroll
        for (int j = 0; j < 9; ++j) sp[j] = s[j];
        const float center = s[4];
        out0[((size_t)b * NPIX + n) * 2 + 0] = center;
        out0[((size_t)b * NPIX + n) * 2 + 1] = (ssum - center) * 0.125f;
    }
}

// ---------------------------------------------------------------------------
// Kernel C: new_v gather + residual, write xr, accumulate partial LN sums.
// grid: (NT, cnb)  block: 256 (thread = channel c)
// ---------------------------------------------------------------------------
__global__ __launch_bounds__(256) void newv_kernel(
    const float* __restrict__ x,
    const float* __restrict__ v,       // [cnb][NPIX][CH]
    const float* __restrict__ scores,  // [cnb][NPIX][9]
    float* __restrict__ xr,            // [BATCH][CH][NPIX] (d_out region)
    float* __restrict__ psum, float* __restrict__ psq,  // [cnb][CH][NT]
    int b0)
{
    const int c    = threadIdx.x;
    const int tile = blockIdx.x;
    const int bl   = blockIdx.y;
    const int b    = b0 + bl;

    const float* vb  = v + (size_t)bl * NPIX * CH;
    const float* sb  = scores + (size_t)bl * NPIX * 9;
    const float* xb  = x  + ((size_t)b * CH + c) * NPIX;
    float*       xrb = xr + ((size_t)b * CH + c) * NPIX;

    const int n0 = tile * NTILE;
    float sum = 0.f, sq = 0.f;
    for (int t = 0; t < NTILE; ++t) {
        const int n = n0 + t;
        const int r = n / WW, col = n % WW;
        const float* sp = sb + (size_t)n * 9;
        float acc = 0.f;
        #pragma unroll
        for (int j = 0; j < 9; ++j) {
            int rr = min(max(r + j / 3 - 1, 0), HH - 1);
            int c2 = min(max(col + j % 3 - 1, 0), WW - 1);
            int nbr = rr * WW + c2;
            acc += sp[j] * vb[(size_t)nbr * CH + c];
        }
        const float val = xb[n] + acc;
        xrb[n] = val;
        sum += val;
        sq  += val * val;
    }
    psum[((size_t)bl * CH + c) * NT + tile] = sum;
    psq [((size_t)bl * CH + c) * NT + tile] = sq;
}

// ---------------------------------------------------------------------------
// Kernel D: reduce partials -> mu, rstd per (b,c).  grid: cnb*CH, block: 64
// ---------------------------------------------------------------------------
__global__ __launch_bounds__(64) void stats_kernel(
    const float* __restrict__ psum, const float* __restrict__ psq,
    float* __restrict__ mu, float* __restrict__ rstd)
{
    const int bc   = blockIdx.x;
    const int lane = threadIdx.x;
    float s = 0.f, q2 = 0.f;
    for (int t = lane; t < NT; t += 64) {
        s  += psum[(size_t)bc * NT + t];
        q2 += psq [(size_t)bc * NT + t];
    }
    #pragma unroll
    for (int off = 32; off >= 1; off >>= 1) {
        s  += __shfl_xor(s,  off, 64);
        q2 += __shfl_xor(q2, off, 64);
    }
    if (lane == 0) {
        const float m   = s / (float)NPIX;
        const float var = q2 / (float)NPIX - m * m;
        mu[bc]   = m;
        rstd[bc] = rsqrtf(var + 1e-5f);
    }
}

// ---------------------------------------------------------------------------
// Kernel E: normalize xr in place.  grid: (NT, cnb)  block: 256 (thread = c)
// ---------------------------------------------------------------------------
__global__ __launch_bounds__(256) void norm_kernel(
    float* __restrict__ xr,
    const float* __restrict__ mu, const float* __restrict__ rstd,
    int b0)
{
    const int c    = threadIdx.x;
    const int tile = blockIdx.x;
    const int bl   = blockIdx.y;
    const int b    = b0 + bl;
    const float m  = mu  [bl * CH + c];
    const float rs = rstd[bl * CH + c];
    float* p = xr + ((size_t)b * CH + c) * NPIX + tile * NTILE;
    #pragma unroll
    for (int t = 0; t < NTILE; ++t) p[t] = (p[t] - m) * rs;
}

// ---------------------------------------------------------------------------
extern "C" void kernel_launch(void* const* d_in, const int* in_sizes, int n_in,
                              void* d_out, int out_size, void* d_ws, size_t ws_size,
                              hipStream_t stream)
{
    const float* x  = (const float*)d_in[0];
    const float* Wq = (const float*)d_in[1];
    const float* bq = (const float*)d_in[2];
    const float* Wk = (const float*)d_in[3];
    const float* bk = (const float*)d_in[4];
    const float* Wv = (const float*)d_in[5];
    const float* bv = (const float*)d_in[6];

    float* out0 = (float*)d_out;                          // [B][N][2]
    float* xr   = out0 + (size_t)BATCH * NPIX * 2;        // [B][C][N]

    // Per-batch scratch footprint (floats):
    const size_t fQ  = (size_t)NPIX * CH;   // q
    const size_t fK  = (size_t)NPIX * CH;   // k
    const size_t fV  = (size_t)NPIX * CH;   // v
    const size_t fS  = (size_t)NPIX * 9;    // scores
    const size_t fPS = (size_t)CH * NT;     // psum
    const size_t fPQ = (size_t)CH * NT;     // psq
    const size_t fMU = (size_t)CH;          // mu
    const size_t fRS = (size_t)CH;          // rstd
    const size_t perBatchFloats = fQ + fK + fV + fS + fPS + fPQ + fMU + fRS;
    const size_t perBatchBytes  = perBatchFloats * sizeof(float);

    int NB = (int)(ws_size / perBatchBytes);
    if (NB < 1)  NB = 1;
    if (NB > BATCH) NB = BATCH;

    float* wq    = (float*)d_ws;
    float* wk    = wq    + (size_t)NB * fQ;
    float* wv    = wk    + (size_t)NB * fK;
    float* wsc   = wv    + (size_t)NB * fV;
    float* wpsum = wsc   + (size_t)NB * fS;
    float* wpsq  = wpsum + (size_t)NB * fPS;
    float* wmu   = wpsq  + (size_t)NB * fPQ;
    float* wrstd = wmu   + (size_t)NB * fMU;

    for (int b0 = 0; b0 < BATCH; b0 += NB) {
        const int cnb = (BATCH - b0 < NB) ? (BATCH - b0) : NB;

        dim3 gA(NPIX / TN, CH / TO, cnb * 3);
        qkv_gemm<<<gA, 256, 0, stream>>>(x, Wq, bq, Wk, bk, Wv, bv,
                                         wq, wk, wv, b0);

        dim3 gB(NPIX / 4, cnb);
        scores_kernel<<<gB, 256, 0, stream>>>(wq, wk, wsc, out0, b0);

        dim3 gC(NT, cnb);
        newv_kernel<<<gC, 256, 0, stream>>>(x, wv, wsc, xr, wpsum, wpsq, b0);

        dim3 gD(cnb * CH);
        stats_kernel<<<gD, 64, 0, stream>>>(wpsum, wpsq, wmu, wrstd);

        dim3 gE(NT, cnb);
        norm_kernel<<<gE, 256, 0, stream>>>(xr, wmu, wrstd, b0);
    }
}

// Round 2
// 321.501 us; speedup vs baseline: 5.0827x; 5.0827x over previous
//
#include <hip/hip_runtime.h>
#include <hip/hip_bf16.h>

using f32x4  = __attribute__((ext_vector_type(4))) float;
using short8 = __attribute__((ext_vector_type(8))) short;
using bf16   = __hip_bfloat16;

constexpr int BATCH = 16;
constexpr int CH    = 256;
constexpr int HH    = 80;
constexpr int WW    = 80;
constexpr int NPIX  = HH * WW;   // 6400

__device__ __forceinline__ float b2f(unsigned short u) {
    union { unsigned int i; float f; } x;
    x.i = ((unsigned int)u) << 16;
    return x.f;
}

// ---------------------------------------------------------------------------
// Kernel 0: convert weights fp32 -> bf16.  grid (CH*CH/256, 3), block 256
// ---------------------------------------------------------------------------
__global__ __launch_bounds__(256) void convert_w(
    const float* __restrict__ Wq, const float* __restrict__ Wk,
    const float* __restrict__ Wv, bf16* __restrict__ Wb)
{
    const int elem = blockIdx.x * 256 + threadIdx.x;
    const int mat  = blockIdx.y;
    const float* src = (mat == 0) ? Wq : (mat == 1) ? Wk : Wv;
    Wb[(size_t)mat * CH * CH + elem] = __float2bfloat16(src[elem]);
}

// ---------------------------------------------------------------------------
// Kernel 1: x [b][c][n] fp32 -> x_t [bl][n][c] bf16 (tiled transpose)
// grid (NPIX/64, CH/64, cnb)  block 256
// ---------------------------------------------------------------------------
__global__ __launch_bounds__(256) void transpose_cast(
    const float* __restrict__ x, bf16* __restrict__ xt, int b0)
{
    __shared__ float t[64][65];
    const int b  = b0 + blockIdx.z;
    const int n0 = blockIdx.x * 64;
    const int c0 = blockIdx.y * 64;
    const float* xb = x + (size_t)b * CH * NPIX;
    const int tid = threadIdx.x;

    {
        const int nl  = tid & 63;
        const int cl0 = tid >> 6;
        #pragma unroll
        for (int i = 0; i < 16; ++i) {
            const int cl = cl0 + i * 4;
            t[cl][nl] = xb[(size_t)(c0 + cl) * NPIX + n0 + nl];
        }
    }
    __syncthreads();
    {
        bf16* xtb = xt + (size_t)blockIdx.z * NPIX * CH;
        const int cl  = tid & 63;
        const int nl0 = tid >> 6;
        #pragma unroll
        for (int i = 0; i < 16; ++i) {
            const int nl = nl0 + i * 4;
            xtb[(size_t)(n0 + nl) * CH + c0 + cl] = __float2bfloat16(t[cl][nl]);
        }
    }
}

// ---------------------------------------------------------------------------
// Kernel 2: MFMA GEMM.  out[n][o] = sum_c xt[n][c] * W[o][c] (+bias)
// q,k: bf16 [bl][n][o].  v: bf16 [bl][o][n] (transposed store).
// grid (NPIX/128, CH/128, cnb*3)  block 256 (4 waves, each 64x64)
// ---------------------------------------------------------------------------
__global__ __launch_bounds__(256) void qkv_mfma(
    const bf16* __restrict__ xt, const bf16* __restrict__ Wb,
    const float* __restrict__ bq, const float* __restrict__ bk,
    const float* __restrict__ bv,
    bf16* __restrict__ qo, bf16* __restrict__ ko, bf16* __restrict__ vt)
{
    const int m  = blockIdx.z % 3;
    const int bl = blockIdx.z / 3;
    const int n0 = blockIdx.x * 128;
    const int o0 = blockIdx.y * 128;
    const bf16*  W    = Wb + (size_t)m * CH * CH;
    const float* bias = (m == 0) ? bq : (m == 1) ? bk : bv;
    const bf16*  A    = xt + (size_t)bl * NPIX * CH;

    // padded rows: 36 shorts = 72B -> odd bank stride, conflict-free b128 reads
    __shared__ short As[128 * 36];
    __shared__ short Bs[128 * 36];

    const int tid = threadIdx.x;
    const int wv  = tid >> 6, ln = tid & 63;
    const int wr  = wv >> 1,  wc = wv & 1;
    const int lm  = ln & 15,  lk = ln >> 4;

    f32x4 acc[4][4];
    #pragma unroll
    for (int i = 0; i < 4; ++i)
        #pragma unroll
        for (int j = 0; j < 4; ++j)
            #pragma unroll
            for (int r = 0; r < 4; ++r) acc[i][j][r] = 0.f;

    for (int k0 = 0; k0 < CH; k0 += 32) {
        #pragma unroll
        for (int it = 0; it < 2; ++it) {
            const int q   = tid + it * 256;
            const int row = q >> 2, ch = q & 3;
            const int4 av = *(const int4*)(A + (size_t)(n0 + row) * CH + k0 + ch * 8);
            *(int4*)((char*)As + row * 72 + ch * 16) = av;
            const int4 wvv = *(const int4*)(W + (size_t)(o0 + row) * CH + k0 + ch * 8);
            *(int4*)((char*)Bs + row * 72 + ch * 16) = wvv;
        }
        __syncthreads();

        short8 afr[4], bfr[4];
        #pragma unroll
        for (int i = 0; i < 4; ++i) {
            const int row = wr * 64 + i * 16 + lm;
            afr[i] = *(const short8*)((const char*)As + row * 72 + lk * 16);
        }
        #pragma unroll
        for (int j = 0; j < 4; ++j) {
            const int row = wc * 64 + j * 16 + lm;
            bfr[j] = *(const short8*)((const char*)Bs + row * 72 + lk * 16);
        }
        #pragma unroll
        for (int i = 0; i < 4; ++i)
            #pragma unroll
            for (int j = 0; j < 4; ++j)
                acc[i][j] = __builtin_amdgcn_mfma_f32_16x16x32_bf16(
                    afr[i], bfr[j], acc[i][j], 0, 0, 0);
        __syncthreads();
    }

    // Epilogue. C/D layout: col(o) = lane&15, row(n) = (lane>>4)*4 + reg
    if (m < 2) {
        bf16* out = (m == 0 ? qo : ko) + (size_t)bl * NPIX * CH;
        #pragma unroll
        for (int j = 0; j < 4; ++j) {
            const int o = o0 + wc * 64 + j * 16 + lm;
            const float bs = bias[o];
            #pragma unroll
            for (int i = 0; i < 4; ++i) {
                const int nb = n0 + wr * 64 + i * 16 + lk * 4;
                #pragma unroll
                for (int r = 0; r < 4; ++r)
                    out[(size_t)(nb + r) * CH + o] = __float2bfloat16(acc[i][j][r] + bs);
            }
        }
    } else {
        bf16* out = vt + (size_t)bl * CH * NPIX;
        #pragma unroll
        for (int j = 0; j < 4; ++j) {
            const int o = o0 + wc * 64 + j * 16 + lm;
            const float bs = bias[o];
            #pragma unroll
            for (int i = 0; i < 4; ++i) {
                const int nb = n0 + wr * 64 + i * 16 + lk * 4;
                ushort4 pk;
                #pragma unroll
                for (int r = 0; r < 4; ++r) {
                    const bf16 h = __float2bfloat16(acc[i][j][r] + bs);
                    ((unsigned short*)&pk)[r] = *(const unsigned short*)&h;
                }
                *(ushort4*)((bf16*)out + (size_t)o * NPIX + nb) = pk;
            }
        }
    }
}

// ---------------------------------------------------------------------------
// Kernel 3: scores[n][j] = dot_c(q[n][:], k[nbr(n,j)][:]), + output0
// grid (NPIX/4, cnb)  block 256 (wave per pixel)
// ---------------------------------------------------------------------------
__global__ __launch_bounds__(256) void scores_kernel(
    const bf16* __restrict__ q, const bf16* __restrict__ k,
    float* __restrict__ scores, float* __restrict__ out0, int b0)
{
    const int wave = threadIdx.x >> 6, lane = threadIdx.x & 63;
    const int n  = blockIdx.x * 4 + wave;
    const int bl = blockIdx.y;
    const int b  = b0 + bl;

    const unsigned short* qrow = (const unsigned short*)(q + ((size_t)bl * NPIX + n) * CH) + lane * 4;
    const unsigned short* kb   = (const unsigned short*)(k + (size_t)bl * NPIX * CH);

    const ushort4 qu = *(const ushort4*)qrow;
    const float q0 = b2f(qu.x), q1 = b2f(qu.y), q2 = b2f(qu.z), q3 = b2f(qu.w);

    const int r = n / WW, col = n % WW;
    float s[9], ssum = 0.f;
    #pragma unroll
    for (int j = 0; j < 9; ++j) {
        const int rr = min(max(r + j / 3 - 1, 0), HH - 1);
        const int c2 = min(max(col + j % 3 - 1, 0), WW - 1);
        const int nbr = rr * WW + c2;
        const ushort4 kv = *(const ushort4*)(kb + (size_t)nbr * CH + lane * 4);
        float d = q0 * b2f(kv.x) + q1 * b2f(kv.y) + q2 * b2f(kv.z) + q3 * b2f(kv.w);
        #pragma unroll
        for (int off = 32; off >= 1; off >>= 1) d += __shfl_xor(d, off, 64);
        s[j] = d;
        ssum += d;
    }
    if (lane == 0) {
        float* sp = scores + ((size_t)bl * NPIX + n) * 9;
        #pragma unroll
        for (int j = 0; j < 9; ++j) sp[j] = s[j];
        const float center = s[4];
        out0[((size_t)b * NPIX + n) * 2 + 0] = center;
        out0[((size_t)b * NPIX + n) * 2 + 1] = (ssum - center) * 0.125f;
    }
}

// ---------------------------------------------------------------------------
// Kernel 4: fused new_v gather + residual + full LayerNorm -> x_out.
// Block owns one (b,c): 25 pixels/thread in registers, block-reduce stats.
// grid (CH, cnb)  block 256
// ---------------------------------------------------------------------------
__global__ __launch_bounds__(256) void newv_ln(
    const float* __restrict__ x, const bf16* __restrict__ vt,
    const float* __restrict__ scores, float* __restrict__ xout, int b0)
{
    const int c  = blockIdx.x;
    const int bl = blockIdx.y;
    const int b  = b0 + bl;
    const int tid = threadIdx.x;

    const unsigned short* vrow = (const unsigned short*)(vt + ((size_t)bl * CH + c) * NPIX);
    const float* xrow = x + ((size_t)b * CH + c) * NPIX;
    const float* sb   = scores + (size_t)bl * NPIX * 9;

    float val[25];
    float sum = 0.f, sq = 0.f;
    #pragma unroll
    for (int it = 0; it < 25; ++it) {
        const int n   = tid + it * 256;
        const int r   = n / WW;
        const int col = n - r * WW;
        const float* sp = sb + (size_t)n * 9;
        const int rm = max(r - 1, 0) * WW;
        const int r0 = r * WW;
        const int rp = min(r + 1, HH - 1) * WW;
        const int cm = max(col - 1, 0);
        const int cp = min(col + 1, WW - 1);
        float a;
        a  = sp[0] * b2f(vrow[rm + cm]) + sp[1] * b2f(vrow[rm + col]) + sp[2] * b2f(vrow[rm + cp]);
        a += sp[3] * b2f(vrow[r0 + cm]) + sp[4] * b2f(vrow[r0 + col]) + sp[5] * b2f(vrow[r0 + cp]);
        a += sp[6] * b2f(vrow[rp + cm]) + sp[7] * b2f(vrow[rp + col]) + sp[8] * b2f(vrow[rp + cp]);
        const float vv = xrow[n] + a;
        val[it] = vv;
        sum += vv;
        sq  += vv * vv;
    }

    #pragma unroll
    for (int off = 32; off >= 1; off >>= 1) {
        sum += __shfl_xor(sum, off, 64);
        sq  += __shfl_xor(sq,  off, 64);
    }
    __shared__ float rs[4], rq[4];
    const int wave = tid >> 6, lane = tid & 63;
    if (lane == 0) { rs[wave] = sum; rq[wave] = sq; }
    __syncthreads();
    sum = rs[0] + rs[1] + rs[2] + rs[3];
    sq  = rq[0] + rq[1] + rq[2] + rq[3];

    const float mu   = sum * (1.f / NPIX);
    const float var  = sq * (1.f / NPIX) - mu * mu;
    const float rstd = rsqrtf(var + 1e-5f);

    float* orow = xout + ((size_t)b * CH + c) * NPIX;
    #pragma unroll
    for (int it = 0; it < 25; ++it) {
        const int n = tid + it * 256;
        orow[n] = (val[it] - mu) * rstd;
    }
}

// ---------------------------------------------------------------------------
extern "C" void kernel_launch(void* const* d_in, const int* in_sizes, int n_in,
                              void* d_out, int out_size, void* d_ws, size_t ws_size,
                              hipStream_t stream)
{
    const float* x  = (const float*)d_in[0];
    const float* Wq = (const float*)d_in[1];
    const float* bq = (const float*)d_in[2];
    const float* Wk = (const float*)d_in[3];
    const float* bk = (const float*)d_in[4];
    const float* Wv = (const float*)d_in[5];
    const float* bv = (const float*)d_in[6];

    float* out0 = (float*)d_out;                       // [B][N][2]
    float* xout = out0 + (size_t)BATCH * NPIX * 2;     // [B][C][N]

    char* ws = (char*)d_ws;
    bf16* Wb = (bf16*)ws;
    ws += (size_t)3 * CH * CH * sizeof(bf16);          // 384 KiB

    const size_t fBF = (size_t)NPIX * CH * sizeof(bf16);   // 3.28 MB
    const size_t fSC = (size_t)NPIX * 9 * sizeof(float);   // 230 KB
    const size_t perBatch = 4 * fBF + fSC;                 // ~13.3 MB

    size_t avail = ws_size - ((size_t)3 * CH * CH * sizeof(bf16));
    int NB = (int)(avail / perBatch);
    if (NB < 1)  NB = 1;
    if (NB > BATCH) NB = BATCH;

    bf16*  xt  = (bf16*)ws;
    bf16*  qb  = (bf16*)(ws + (size_t)NB * fBF);
    bf16*  kb  = (bf16*)(ws + (size_t)NB * fBF * 2);
    bf16*  vt  = (bf16*)(ws + (size_t)NB * fBF * 3);
    float* sc  = (float*)(ws + (size_t)NB * fBF * 4);

    convert_w<<<dim3(CH * CH / 256, 3), 256, 0, stream>>>(Wq, Wk, Wv, Wb);

    for (int b0 = 0; b0 < BATCH; b0 += NB) {
        const int cnb = (BATCH - b0 < NB) ? (BATCH - b0) : NB;

        transpose_cast<<<dim3(NPIX / 64, CH / 64, cnb), 256, 0, stream>>>(x, xt, b0);

        qkv_mfma<<<dim3(NPIX / 128, CH / 128, cnb * 3), 256, 0, stream>>>(
            xt, Wb, bq, bk, bv, qb, kb, vt);

        scores_kernel<<<dim3(NPIX / 4, cnb), 256, 0, stream>>>(qb, kb, sc, out0, b0);

        newv_ln<<<dim3(CH, cnb), 256, 0, stream>>>(x, vt, sc, xout, b0);
    }
}